// Round 1
// baseline (9374.290 us; speedup 1.0000x reference)
//
#include <hip/hip_runtime.h>

// LiquidLayer: h_t = h + DT*(-h/tau + tanh(xW_t + h U^T + b)), T=1024 steps.
// Out = [h_final (32x1024) | states (32x1024x1024)] f32.
// Phase 1: xW GEMM (f32, tiled) written in-place into states region.
// Phase 2: ONE persistent kernel, 128 WGs x 1 wave; per-step grid exchange of
//          bf16 h through L3 with a flag-array barrier (agent-scope atomics).
//          U fragments register-resident (loaded once); h f32 register-resident
//          (each lane owns the 4 (b,j) elements it writes).

#define DT 0.1f
#define BB 32
#define TT 1024
#define II 512
#define HH 1024

typedef __attribute__((ext_vector_type(4))) float f32x4;
typedef __attribute__((ext_vector_type(8))) short s16x8;

__device__ __forceinline__ unsigned short f2bf(float f) {
  unsigned int u = __builtin_bit_cast(unsigned int, f);
  u += 0x7fffu + ((u >> 16) & 1u);  // RNE
  return (unsigned short)(u >> 16);
}

// ---------------- U f32 -> bf16 (runs every call; ws is re-poisoned) --------
__global__ __launch_bounds__(256) void cvt_u_kernel(const float* __restrict__ U,
                                                    unsigned short* __restrict__ Ub) {
  int i4 = (blockIdx.x * 256 + threadIdx.x) * 4;
  float4 v = *(const float4*)(U + i4);
  ushort4 o;
  o.x = f2bf(v.x); o.y = f2bf(v.y); o.z = f2bf(v.z); o.w = f2bf(v.w);
  *(ushort4*)(Ub + i4) = o;
}

// ---------------- Phase 1: xW[m][n] = sum_k x[m][k] * W[n][k] (f32) ---------
// M=32768, N=1024, K=512. Block tile 128x128, 256 threads, 8x8 per thread.
#define P1_LDK 36  // LDS row stride (words): pad 32->36; even, 16B-aligned rows

__global__ __launch_bounds__(256) void xw_gemm(const float* __restrict__ x,
                                               const float* __restrict__ W,
                                               float* __restrict__ out) {
  __shared__ __align__(16) float Xs[128 * P1_LDK];
  __shared__ __align__(16) float Ws_s[128 * P1_LDK];
  const int tid = threadIdx.x;
  const int m0 = blockIdx.y * 128;
  const int n0 = blockIdx.x * 128;
  const int ty = tid >> 4;       // 0..15
  const int tx = tid & 15;       // 0..15
  const int lrow = tid >> 3;     // loader: 0..31
  const int lf = tid & 7;        // loader: float4 column 0..7

  float acc[8][8];
#pragma unroll
  for (int i = 0; i < 8; ++i)
#pragma unroll
    for (int j = 0; j < 8; ++j) acc[i][j] = 0.0f;

  for (int kk = 0; kk < II; kk += 32) {
#pragma unroll
    for (int p = 0; p < 4; ++p) {
      int r = lrow + 32 * p;
      float4 vx = *(const float4*)&x[(m0 + r) * II + kk + 4 * lf];
      *(float4*)&Xs[r * P1_LDK + 4 * lf] = vx;
      float4 vw = *(const float4*)&W[(n0 + r) * II + kk + 4 * lf];
      *(float4*)&Ws_s[r * P1_LDK + 4 * lf] = vw;
    }
    __syncthreads();
#pragma unroll
    for (int kq = 0; kq < 32; kq += 4) {
      float4 a[8], b[8];
#pragma unroll
      for (int i = 0; i < 4; ++i) {
        a[i]     = *(const float4*)&Xs[(ty * 4 + i) * P1_LDK + kq];
        a[i + 4] = *(const float4*)&Xs[(ty * 4 + i + 64) * P1_LDK + kq];
      }
#pragma unroll
      for (int j = 0; j < 8; ++j)
        b[j] = *(const float4*)&Ws_s[(tx + 16 * j) * P1_LDK + kq];
#pragma unroll
      for (int i = 0; i < 8; ++i)
#pragma unroll
        for (int j = 0; j < 8; ++j) {
          acc[i][j] += a[i].x * b[j].x;
          acc[i][j] += a[i].y * b[j].y;
          acc[i][j] += a[i].z * b[j].z;
          acc[i][j] += a[i].w * b[j].w;
        }
    }
    __syncthreads();
  }
#pragma unroll
  for (int i = 0; i < 8; ++i) {
    int m = m0 + ty * 4 + (i < 4 ? i : 64 + i - 4);
#pragma unroll
    for (int j = 0; j < 8; ++j)
      out[m * HH + n0 + tx + 16 * j] = acc[i][j];
  }
}

// ---------------- Phase 2: persistent scan ----------------------------------
// 128 WGs x 64 threads. WG = (mg in 0..1) x (jg in 0..63):
//   owns batches mg*16..+16, cols jg*16..+16.
// The two mg groups are fully independent (disjoint flags / h rows / states).
// Barrier: flags[mg][w] = #steps WG w completed (monotonic). Wait-all >= t,
// then acquire fence (buffer_inv) so plain h loads re-fetch from the coherent
// point; release fence (wbl2 + vmcnt drain) before the flag store.
__global__ __launch_bounds__(64, 1) void liquid_scan(
    const unsigned short* __restrict__ Ub,   // U bf16 [1024][1024]
    unsigned short* __restrict__ hbuf,       // bf16 [2][32][1024] (exchange)
    int* flags,                              // [2][64]
    float* __restrict__ hf,                  // h_final f32 [32][1024]
    float* __restrict__ states,              // [32][1024][1024]; holds xW at t
    const float* __restrict__ bias,
    const float* __restrict__ tau) {
  const int l = threadIdx.x;
  const int wg = blockIdx.x;
  const int mg = wg >> 6;            // 0..1
  const int jg = wg & 63;            // 0..63
  const int n = l & 15;              // MFMA col
  const int q = l >> 4;              // 0..3
  const int j = jg * 16 + n;         // this lane's output column
  const int arow = mg * 16 + n;      // A-fragment h row

  // B fragments, register-resident for the whole scan:
  // lane holds B[k=q*8+i][n] = U[j][kc*32 + q*8 + i], contiguous 16 B.
  s16x8 ufrag[32];
#pragma unroll
  for (int kc = 0; kc < 32; ++kc)
    ufrag[kc] = *(const s16x8*)(Ub + (size_t)j * HH + kc * 32 + q * 8);

  const float bj = bias[j];
  const float invt = 1.0f / tau[j];
  int* const myflags = flags + mg * 64;

  // h f32 register-resident: lane owns rows b = mg*16 + q*4 + r, col j.
  float hold[4] = {0.f, 0.f, 0.f, 0.f};
  float xw[4];
#pragma unroll
  for (int r = 0; r < 4; ++r)
    xw[r] = states[((size_t)(mg * 16 + q * 4 + r) * TT + 0) * HH + j];

  for (int t = 0; t < TT; ++t) {
    const unsigned short* hin = hbuf + (size_t)(t & 1) * (BB * HH);
    unsigned short* hout = hbuf + (size_t)((t + 1) & 1) * (BB * HH);

    if (t > 0) {
      // wait: all 64 WGs of my batch-group finished step t-1.
      // agent-scope atomic loads bypass the (non-coherent) per-XCD L2.
      for (;;) {
        int f = __hip_atomic_load(&myflags[l], __ATOMIC_RELAXED,
                                  __HIP_MEMORY_SCOPE_AGENT);
        if (__all(f >= t)) break;
      }
      __builtin_amdgcn_fence(__ATOMIC_ACQUIRE, "agent");
    }

    // A fragments straight from global (L3-coherent after the acquire fence):
    // lane holds A[m=l&15][k=q*8+i] = h[arow][kc*32 + q*8 + i], 16 B each.
    s16x8 af[32];
#pragma unroll
    for (int kc = 0; kc < 32; ++kc)
      af[kc] = *(const s16x8*)(hin + (size_t)arow * HH + kc * 32 + q * 8);

    // prefetch next step's xw under the MFMA chain (lane-private addresses,
    // written only by this lane at step t+1 -> race-free).
    const int tn = (t + 1 < TT) ? t + 1 : TT - 1;
    float xwn[4];
#pragma unroll
    for (int r = 0; r < 4; ++r)
      xwn[r] = states[((size_t)(mg * 16 + q * 4 + r) * TT + tn) * HH + j];

    // 4 accumulator chains to break MFMA latency serialization.
    f32x4 a0 = {0.f, 0.f, 0.f, 0.f}, a1 = {0.f, 0.f, 0.f, 0.f};
    f32x4 a2 = {0.f, 0.f, 0.f, 0.f}, a3 = {0.f, 0.f, 0.f, 0.f};
#pragma unroll
    for (int kc = 0; kc < 32; kc += 4) {
      a0 = __builtin_amdgcn_mfma_f32_16x16x32_bf16(af[kc + 0], ufrag[kc + 0], a0, 0, 0, 0);
      a1 = __builtin_amdgcn_mfma_f32_16x16x32_bf16(af[kc + 1], ufrag[kc + 1], a1, 0, 0, 0);
      a2 = __builtin_amdgcn_mfma_f32_16x16x32_bf16(af[kc + 2], ufrag[kc + 2], a2, 0, 0, 0);
      a3 = __builtin_amdgcn_mfma_f32_16x16x32_bf16(af[kc + 3], ufrag[kc + 3], a3, 0, 0, 0);
    }
    f32x4 acc = (a0 + a1) + (a2 + a3);

    // epilogue: D[row=q*4+r][col=n] -> batch b = mg*16+q*4+r, col j.
#pragma unroll
    for (int r = 0; r < 4; ++r) {
      const int b = mg * 16 + q * 4 + r;
      float pre = xw[r] + acc[r] + bj;
      float act = tanhf(pre);
      float hnew = hold[r] + DT * (act - invt * hold[r]);
      hold[r] = hnew;
      states[((size_t)b * TT + t) * HH + j] = hnew;
      hout[b * HH + j] = f2bf(hnew);
      xw[r] = xwn[r];
    }

    // publish: drain stores to the coherent point, then bump my flag.
    __builtin_amdgcn_fence(__ATOMIC_RELEASE, "agent");
    if (l == 0)
      __hip_atomic_store(&myflags[jg], t + 1, __ATOMIC_RELAXED,
                         __HIP_MEMORY_SCOPE_AGENT);
  }

  // h_final
#pragma unroll
  for (int r = 0; r < 4; ++r)
    hf[(mg * 16 + q * 4 + r) * HH + j] = hold[r];
}

// ---------------------------------------------------------------------------
extern "C" void kernel_launch(void* const* d_in, const int* in_sizes, int n_in,
                              void* d_out, int out_size, void* d_ws, size_t ws_size,
                              hipStream_t stream) {
  const float* x    = (const float*)d_in[0];
  const float* W    = (const float*)d_in[1];
  const float* U    = (const float*)d_in[2];
  const float* bias = (const float*)d_in[3];
  const float* tau  = (const float*)d_in[4];

  float* out = (float*)d_out;
  float* hf = out;                         // [32][1024] -> h_final
  float* states = out + BB * HH;           // [32][1024][1024]

  unsigned short* Ub = (unsigned short*)d_ws;            // 2 MB
  unsigned short* hbuf = Ub + (size_t)HH * HH;           // 128 KB (2 buffers)
  int* flags = (int*)(hbuf + 2 * BB * HH);               // 512 B

  // init exchange buffers + flags (ws is re-poisoned before every call)
  hipMemsetAsync(hbuf, 0,
                 2 * BB * HH * sizeof(unsigned short) + 128 * sizeof(int),
                 stream);

  cvt_u_kernel<<<(HH * HH) / (256 * 4), 256, 0, stream>>>(U, Ub);

  // Phase 1: xW into the states region (overwritten in-place by the scan).
  xw_gemm<<<dim3(HH / 128, (BB * TT) / 128), 256, 0, stream>>>(x, W, states);

  // Phase 2: single persistent kernel; 128 WGs (<=256 CUs => co-resident).
  liquid_scan<<<128, 64, 0, stream>>>(Ub, hbuf, flags, hf, states, bias, tau);
}

// Round 3
// 5394.264 us; speedup vs baseline: 1.7378x; 1.7378x over previous
//
#include <hip/hip_runtime.h>

// LiquidLayer: h_t = h + DT*(-h/tau + tanh(xW_t + h U^T + b)), T=1024 steps.
// Out = [h_final (32x1024) | states (32x1024x1024)] f32.
// Phase 1: xW GEMM (f32, tiled) written in-place into states region.
// Phase 2: ONE persistent kernel, 128 WGs x 1 wave. Cross-WG exchange of bf16 h
//          through the coherent point (L3) using SYSTEM-scope relaxed atomics
//          (sc0+sc1: bypass L1 and the non-coherent per-XCD L2) -- no
//          buffer_inv / buffer_wbl2 cache maintenance anywhere.
//          Barrier = one monotonic atomicAdd arrival counter per batch-group
//          (target 64*t) + s_sleep-backoff poll + 1s realtime watchdog so a
//          broken protocol can NEVER hang the container.

#define DT 0.1f
#define BB 32
#define TT 1024
#define II 512
#define HH 1024

typedef __attribute__((ext_vector_type(4))) float f32x4;
typedef __attribute__((ext_vector_type(8))) short s16x8;

__device__ __forceinline__ unsigned short f2bf(float f) {
  unsigned int u = __builtin_bit_cast(unsigned int, f);
  u += 0x7fffu + ((u >> 16) & 1u);  // RNE
  return (unsigned short)(u >> 16);
}

// tanh via HW exp2 + rcp: tanh(x) = 1 - 2/(e^{2x}+1). Exact at +-inf,
// |err| ~1e-6 << bf16 h quantization (2e-3). ~8 instr vs ~40 for ocml tanhf.
__device__ __forceinline__ float fast_tanh(float x) {
  float z = __expf(2.0f * x);                   // v_exp_f32 path
  return 1.0f - 2.0f * __builtin_amdgcn_rcpf(z + 1.0f);
}

// ---------------- U f32 -> bf16 (runs every call; ws is re-poisoned) --------
__global__ __launch_bounds__(256) void cvt_u_kernel(const float* __restrict__ U,
                                                    unsigned short* __restrict__ Ub) {
  int i4 = (blockIdx.x * 256 + threadIdx.x) * 4;
  float4 v = *(const float4*)(U + i4);
  ushort4 o;
  o.x = f2bf(v.x); o.y = f2bf(v.y); o.z = f2bf(v.z); o.w = f2bf(v.w);
  *(ushort4*)(Ub + i4) = o;
}

// ---------------- Phase 1: xW[m][n] = sum_k x[m][k] * W[n][k] (f32) ---------
// M=32768, N=1024, K=512. Block tile 128x128, 256 threads, 8x8 per thread.
#define P1_LDK 36  // LDS row stride (words): pad 32->36; even, 16B-aligned rows

__global__ __launch_bounds__(256) void xw_gemm(const float* __restrict__ x,
                                               const float* __restrict__ W,
                                               float* __restrict__ out) {
  __shared__ __align__(16) float Xs[128 * P1_LDK];
  __shared__ __align__(16) float Ws_s[128 * P1_LDK];
  const int tid = threadIdx.x;
  const int m0 = blockIdx.y * 128;
  const int n0 = blockIdx.x * 128;
  const int ty = tid >> 4;       // 0..15
  const int tx = tid & 15;       // 0..15
  const int lrow = tid >> 3;     // loader: 0..31
  const int lf = tid & 7;        // loader: float4 column 0..7

  float acc[8][8];
#pragma unroll
  for (int i = 0; i < 8; ++i)
#pragma unroll
    for (int j = 0; j < 8; ++j) acc[i][j] = 0.0f;

  for (int kk = 0; kk < II; kk += 32) {
#pragma unroll
    for (int p = 0; p < 4; ++p) {
      int r = lrow + 32 * p;
      float4 vx = *(const float4*)&x[(m0 + r) * II + kk + 4 * lf];
      *(float4*)&Xs[r * P1_LDK + 4 * lf] = vx;
      float4 vw = *(const float4*)&W[(n0 + r) * II + kk + 4 * lf];
      *(float4*)&Ws_s[r * P1_LDK + 4 * lf] = vw;
    }
    __syncthreads();
#pragma unroll
    for (int kq = 0; kq < 32; kq += 4) {
      float4 a[8], b[8];
#pragma unroll
      for (int i = 0; i < 4; ++i) {
        a[i]     = *(const float4*)&Xs[(ty * 4 + i) * P1_LDK + kq];
        a[i + 4] = *(const float4*)&Xs[(ty * 4 + i + 64) * P1_LDK + kq];
      }
#pragma unroll
      for (int j = 0; j < 8; ++j)
        b[j] = *(const float4*)&Ws_s[(tx + 16 * j) * P1_LDK + kq];
#pragma unroll
      for (int i = 0; i < 8; ++i)
#pragma unroll
        for (int j = 0; j < 8; ++j) {
          acc[i][j] += a[i].x * b[j].x;
          acc[i][j] += a[i].y * b[j].y;
          acc[i][j] += a[i].z * b[j].z;
          acc[i][j] += a[i].w * b[j].w;
        }
    }
    __syncthreads();
  }
#pragma unroll
  for (int i = 0; i < 8; ++i) {
    int m = m0 + ty * 4 + (i < 4 ? i : 64 + i - 4);
#pragma unroll
    for (int j = 0; j < 8; ++j)
      out[m * HH + n0 + tx + 16 * j] = acc[i][j];
  }
}

// ---------------- Phase 2: persistent scan ----------------------------------
// 128 WGs x 64 threads (1 wave), co-resident on 256 CUs. WG = (mg 0..1) x
// (jg 0..63): owns batches mg*16..+16, cols jg*16..+16. The two mg halves are
// fully independent (disjoint counters / h rows / states rows).
//
// Coherence protocol (NO cache-maintenance ops):
//  - hbuf + arrival counters touched ONLY via SYSTEM-scope relaxed atomics
//    (sc0+sc1: bypass L1/L2, served at the coherent point) => never stale.
//  - producer: h stores (sys) -> s_waitcnt vmcnt(0) -> atomicAdd(cnt, sys).
//  - consumer: poll cnt >= 64*t (s_sleep backoff) -> sched_barrier -> h loads.
//  - states / hf are lane-private or kernel-final: normal cached accesses,
//    issued AFTER the arrival add (off the cross-WG critical path).
//  - watchdog: absolute 1s deadline (s_memrealtime, 100 MHz) -> a protocol
//    failure produces a fast wrong answer, never a hung container.
__global__ __launch_bounds__(64, 1) void liquid_scan(
    const unsigned short* __restrict__ Ub,   // U bf16 [1024][1024]
    unsigned short* hbuf,                    // bf16 [2][32][1024] (exchange)
    int* arrivals,                           // [2] counters, 128 B apart
    float* __restrict__ hf,                  // h_final f32 [32][1024]
    float* __restrict__ states,              // [32][1024][1024]; holds xW at t
    const float* __restrict__ bias,
    const float* __restrict__ tau) {
  const int l = threadIdx.x;
  const int wg = blockIdx.x;
  const int mg = wg >> 6;            // 0..1
  const int jg = wg & 63;            // 0..63
  const int n = l & 15;              // MFMA col
  const int q = l >> 4;              // 0..3
  const int j = jg * 16 + n;         // this lane's output column
  const int arow = mg * 16 + n;      // A-fragment h row

  const unsigned long long deadline =
      __builtin_amdgcn_s_memrealtime() + 100000000ULL;  // +1 s @ 100 MHz

  // B fragments: lane holds B[k=q*8+i][n] = U[j][kc*32 + q*8 + i], 16 B each.
  s16x8 ufrag[32];
#pragma unroll
  for (int kc = 0; kc < 32; ++kc)
    ufrag[kc] = *(const s16x8*)(Ub + (size_t)j * HH + kc * 32 + q * 8);

  const float bj = bias[j];
  const float invt = 1.0f / tau[j];
  int* const cnt = arrivals + mg * 32;   // 128 B apart per group

  // h f32 register-resident: lane owns rows b = mg*16 + q*4 + r, col j.
  float hold[4] = {0.f, 0.f, 0.f, 0.f};
  float xw[4];
#pragma unroll
  for (int r = 0; r < 4; ++r)
    xw[r] = states[((size_t)(mg * 16 + q * 4 + r) * TT + 0) * HH + j];

  bool dead = false;
  for (int t = 0; t < TT; ++t) {
    const unsigned short* hin = hbuf + (size_t)(t & 1) * (BB * HH);
    unsigned short* hout = hbuf + (size_t)((t + 1) & 1) * (BB * HH);

    // prefetch next step's xw EARLY (lane-private; latency hides under the
    // barrier wait).
    const int tn = (t + 1 < TT) ? t + 1 : TT - 1;
    float xwn[4];
#pragma unroll
    for (int r = 0; r < 4; ++r)
      xwn[r] = states[((size_t)(mg * 16 + q * 4 + r) * TT + tn) * HH + j];

    if (t > 0) {
      const int target = 64 * t;   // all 64 WGs of my group finished step t-1
      while (__hip_atomic_load(cnt, __ATOMIC_RELAXED,
                               __HIP_MEMORY_SCOPE_SYSTEM) < target) {
        __builtin_amdgcn_s_sleep(1);
        if (__builtin_amdgcn_s_memrealtime() > deadline) { dead = true; break; }
      }
      if (dead) break;
      __builtin_amdgcn_sched_barrier(0);
    }

    // A fragments from the coherent point (8B system-scope loads):
    // lane holds A[m=l&15][k=q*8+i] = h[arow][kc*32 + q*8 + i].
    const unsigned long long* hrow =
        (const unsigned long long*)(hin + (size_t)arow * HH);
    s16x8 af[32];
#pragma unroll
    for (int kc = 0; kc < 32; ++kc) {
      unsigned long long lo = __hip_atomic_load(
          hrow + kc * 8 + q * 2, __ATOMIC_RELAXED, __HIP_MEMORY_SCOPE_SYSTEM);
      unsigned long long hi = __hip_atomic_load(
          hrow + kc * 8 + q * 2 + 1, __ATOMIC_RELAXED, __HIP_MEMORY_SCOPE_SYSTEM);
      union { unsigned long long u[2]; s16x8 v; } c;
      c.u[0] = lo; c.u[1] = hi;
      af[kc] = c.v;
    }

    // 4 accumulator chains to break MFMA latency serialization.
    f32x4 a0 = {0.f, 0.f, 0.f, 0.f}, a1 = {0.f, 0.f, 0.f, 0.f};
    f32x4 a2 = {0.f, 0.f, 0.f, 0.f}, a3 = {0.f, 0.f, 0.f, 0.f};
#pragma unroll
    for (int kc = 0; kc < 32; kc += 4) {
      a0 = __builtin_amdgcn_mfma_f32_16x16x32_bf16(af[kc + 0], ufrag[kc + 0], a0, 0, 0, 0);
      a1 = __builtin_amdgcn_mfma_f32_16x16x32_bf16(af[kc + 1], ufrag[kc + 1], a1, 0, 0, 0);
      a2 = __builtin_amdgcn_mfma_f32_16x16x32_bf16(af[kc + 2], ufrag[kc + 2], a2, 0, 0, 0);
      a3 = __builtin_amdgcn_mfma_f32_16x16x32_bf16(af[kc + 3], ufrag[kc + 3], a3, 0, 0, 0);
    }
    f32x4 acc = (a0 + a1) + (a2 + a3);

    // epilogue: D[row=q*4+r][col=n] -> batch b = mg*16+q*4+r, col j.
    float hn[4];
#pragma unroll
    for (int r = 0; r < 4; ++r) {
      const int b = mg * 16 + q * 4 + r;
      float pre = xw[r] + acc[r] + bj;
      float act = fast_tanh(pre);
      float hnew = hold[r] + DT * (act - invt * hold[r]);
      hold[r] = hnew;
      hn[r] = hnew;
      __hip_atomic_store(hout + b * HH + j, f2bf(hnew), __ATOMIC_RELAXED,
                         __HIP_MEMORY_SCOPE_SYSTEM);
      xw[r] = xwn[r];
    }

    // publish: wait for the h-stores to reach the coherent point, then bump
    // the arrival counter.
    asm volatile("s_waitcnt vmcnt(0)" ::: "memory");
    if (l == 0)
      __hip_atomic_fetch_add(cnt, 1, __ATOMIC_RELAXED,
                             __HIP_MEMORY_SCOPE_SYSTEM);

    // states stores: lane-private, read by nobody else -> normal cached
    // stores AFTER the arrival add (off the cross-WG critical path).
#pragma unroll
    for (int r = 0; r < 4; ++r) {
      const int b = mg * 16 + q * 4 + r;
      states[((size_t)b * TT + t) * HH + j] = hn[r];
    }
  }

  // h_final
#pragma unroll
  for (int r = 0; r < 4; ++r)
    hf[(mg * 16 + q * 4 + r) * HH + j] = hold[r];
}

// ---------------------------------------------------------------------------
extern "C" void kernel_launch(void* const* d_in, const int* in_sizes, int n_in,
                              void* d_out, int out_size, void* d_ws, size_t ws_size,
                              hipStream_t stream) {
  const float* x    = (const float*)d_in[0];
  const float* W    = (const float*)d_in[1];
  const float* U    = (const float*)d_in[2];
  const float* bias = (const float*)d_in[3];
  const float* tau  = (const float*)d_in[4];

  float* out = (float*)d_out;
  float* hf = out;                         // [32][1024] -> h_final
  float* states = out + BB * HH;           // [32][1024][1024]

  unsigned short* Ub = (unsigned short*)d_ws;            // 2 MB
  unsigned short* hbuf = Ub + (size_t)HH * HH;           // 128 KB (2 buffers)
  int* arrivals = (int*)(hbuf + 2 * BB * HH);            // 256 B

  // init exchange buffers + counters (ws is re-poisoned before every call)
  hipMemsetAsync(hbuf, 0,
                 2 * BB * HH * sizeof(unsigned short) + 64 * sizeof(int),
                 stream);

  cvt_u_kernel<<<(HH * HH) / (256 * 4), 256, 0, stream>>>(U, Ub);

  // Phase 1: xW into the states region (overwritten in-place by the scan).
  xw_gemm<<<dim3(HH / 128, (BB * TT) / 128), 256, 0, stream>>>(x, W, states);

  // Phase 2: single persistent kernel; 128 WGs (<=256 CUs => co-resident).
  liquid_scan<<<128, 64, 0, stream>>>(Ub, hbuf, arrivals, hf, states, bias, tau);
}